// Round 5
// baseline (218.980 us; speedup 1.0000x reference)
//
#include <hip/hip_runtime.h>
#include <hip/hip_bf16.h>
#include <stdint.h>

// ---------------- problem constants ----------------
#define NB   32
#define NC   256
#define NOC  256
#define HWD  56
#define NPIX 3136      // 56*56
#define PW   58        // padded row width
#define PPIX 3364      // 58*58
#define KTOT 2304      // 9 * 256
#define MOD  512       // fc1 out channels
#define GAPD 16

// workspace layout (bytes)
#define XBT_BYTES ((size_t)NB * PPIX * NC * 2)            // 55,115,776
#define WA_BYTES  ((size_t)NB * NOC * KTOT * 2)           // 37,748,736

typedef __bf16 bf16x8 __attribute__((ext_vector_type(8)));
typedef float  f32x4  __attribute__((ext_vector_type(4)));
typedef unsigned short u16x8 __attribute__((ext_vector_type(8)));

__device__ __forceinline__ unsigned short f2bf(float f) {
    union { float f; unsigned int u; } v; v.f = f;
    unsigned int u = v.u;
    return (unsigned short)((u + 0x7FFFu + ((u >> 16) & 1u)) >> 16);
}

// ---------------- P1: SE network (one block, 512 threads) ----------------
__global__ void se_kernel(const float* __restrict__ gap,
                          const float* __restrict__ rw, const float* __restrict__ rb,
                          const float* __restrict__ f1w, float* __restrict__ a2) {
    __shared__ float sgap[NB * NC];
    __shared__ float sg[NB * GAPD];
    int t = threadIdx.x; // 0..511
    #pragma unroll
    for (int i = 0; i < 16; ++i) sgap[i * 512 + t] = gap[i * 512 + t];
    __syncthreads();
    {
        int b = t >> 4, tt = t & 15;
        float s = rb[tt];
        for (int c = 0; c < NC; ++c) s += sgap[b * NC + c] * rw[tt * NC + c];
        sg[b * GAPD + tt] = s;
    }
    __syncthreads();
    for (int i = 0; i < 32; ++i) {
        int o = i * 512 + t;
        int b = o >> 9, m = o & 511;
        float s = 0.f;
        #pragma unroll
        for (int tt = 0; tt < GAPD; ++tt) s += sg[b * GAPD + tt] * f1w[m * GAPD + tt];
        a2[o] = 1.0f / (1.0f + __expf(-s));
    }
}

// ---------------- P2: per-batch conv weights; one block per oc, loop over b ----------------
__global__ void wk_kernel(const float* __restrict__ a2,
                          const float* __restrict__ f2w, const float* __restrict__ f2b,
                          unsigned short* __restrict__ wa) {
    __shared__ float sw[KTOT];
    __shared__ float sbv[KTOT];
    __shared__ float sa[2 * NB];
    int oc = blockIdx.x, c = threadIdx.x;
    const float4* wsrc = (const float4*)(f2w + (size_t)oc * KTOT);
    const float4* bsrc = (const float4*)(f2b + (size_t)oc * KTOT);
    #pragma unroll
    for (int i = 0; i < 3; ++i) {
        int idx = i * 256 + c;
        if (idx < 576) {
            ((float4*)sw)[idx] = wsrc[idx];
            ((float4*)sbv)[idx] = bsrc[idx];
        }
    }
    if (c < 64) sa[c] = a2[(c >> 1) * MOD + 2 * oc + (c & 1)];
    __syncthreads();
    float w9[9], b9[9];
    #pragma unroll
    for (int s = 0; s < 9; ++s) { w9[s] = sw[c * 9 + s]; b9[s] = sbv[c * 9 + s]; }
    bool hi = (c * 9 + 8) >= 1152;   // if any of this thread's 9 use a1 (rem>=1152)
    for (int b = 0; b < NB; ++b) {
        float a0 = sa[2 * b], a1 = sa[2 * b + 1];
        unsigned short* dst = wa + (size_t)(b * NOC + oc) * KTOT;
        #pragma unroll
        for (int s = 0; s < 9; ++s) {
            float a = ((c * 9 + s) >= 1152) ? a1 : a0;
            dst[s * NC + c] = f2bf(a * w9[s] + b9[s]);
        }
    }
    (void)hi;
}

// ---------------- P3: zero the halo of xbt ----------------
__global__ void halo_kernel(unsigned short* __restrict__ xbt) {
    int b = blockIdx.x, t = threadIdx.x;
    unsigned short* xb = xbt + (size_t)b * PPIX * NC;
    u16x8 z = {};
    for (int i = t; i < 3712; i += 256) {
        int r = (i >= 1856) ? 1 : 0;
        int c = i - r * 1856;
        int pix = r * (57 * 58) + (c >> 5);
        *(u16x8*)(xb + (size_t)pix * NC + (c & 31) * 8) = z;
    }
    for (int i = t; i < 3584; i += 256) {
        int row = 1 + (i >> 6);
        int side = (i >> 5) & 1;
        int pix = row * PW + side * 57;
        *(u16x8*)(xb + (size_t)pix * NC + (i & 31) * 8) = z;
    }
}

// ---------------- P4: x -> bf16 NHWC with halo, fused GAP partial sums ----------------
#define TSTR 59
__global__ void xpose_kernel(const float* __restrict__ x, unsigned short* __restrict__ xbt,
                             float* __restrict__ gap) {
    __shared__ unsigned short tile[NC * TSTR];
    int py = blockIdx.x, b = blockIdx.y, t = threadIdx.x;
    int wv = t >> 6, l = t & 63;
    const float* xs = x + (size_t)b * NC * NPIX + py * HWD;
    int q = l & 15;
    int rb4 = l >> 4;
    #pragma unroll
    for (int it = 0; it < 16; ++it) {
        int c = wv * 64 + it * 4 + rb4;
        if (q < 14) {
            float4 v = *(const float4*)(xs + (size_t)c * NPIX + q * 4);
            unsigned short* tr = tile + c * TSTR + q * 4;
            tr[0] = f2bf(v.x); tr[1] = f2bf(v.y); tr[2] = f2bf(v.z); tr[3] = f2bf(v.w);
        }
    }
    __syncthreads();
    {
        float s = 0.f;
        #pragma unroll
        for (int px = 0; px < 56; ++px) {
            union { unsigned int u; float f; } cv;
            cv.u = ((unsigned int)tile[t * TSTR + px]) << 16;
            s += cv.f;
        }
        atomicAdd(&gap[b * NC + t], s * (1.0f / NPIX));
    }
    int cch = t & 31, pg = t >> 5;
    for (int i = 0; i < 7; ++i) {
        int px = pg * 7 + i;
        u16x8 v;
        #pragma unroll
        for (int j = 0; j < 8; ++j) v[j] = tile[(cch * 8 + j) * TSTR + px];
        *(u16x8*)(xbt + ((size_t)b * PPIX + (size_t)(1 + py) * PW + 1 + px) * NC + cch * 8) = v;
    }
}

// ---------------- main GEMM: 256oc x 160px tile, 4 waves (128x80 each), 3-slice ring ----------------
// K = 2304 = 72 phases of BK=32. Slice = A[256][32] + B[160][32] bf16 = 26 KB; 3 slices = 78 KB
// -> 2 blocks/CU co-resident (independent barriers break CU lockstep).
// Rows are 64 B; LDS uses 128 B pair-units (2 rows), phys chunk p3 = ((kq<<1)|sub) ^ (u&7).
// Staging: 26 wave-instrs of 64 x 16 B; A = instr i 0..3 (all waves), B = i 4..6 (e<26).
// Issue distance 2 (after barrier -> WAR-safe); uniform counted vmcnt(6).
#define SLICE 26624
#define BOFF  16384
#define PXT   160

__global__ __launch_bounds__(256, 2) void conv_gemm(
    const unsigned short* __restrict__ wa,   // [32][256][2304] bf16
    const unsigned short* __restrict__ xbt,  // [32][3364][256] bf16 (padded NHWC)
    float* __restrict__ out)                 // [32][256][3136]
{
    __shared__ __attribute__((aligned(16))) char lds[3 * SLICE];  // 79872 B

    // XCD swizzle: 640 blocks = 8 XCD * 80; 4 whole batches per XCD
    const int bid = blockIdx.x;
    const int wg  = (bid & 7) * 80 + (bid >> 3);
    const int b   = wg / 20, nt = wg % 20;

    const int t = threadIdx.x;
    const int w = t >> 6, l = t & 63;            // 4 waves
    const int wm = w >> 1, wn = w & 1;           // 2M x 2N, wave tile 128oc x 80px

    const unsigned short* waB = wa + (size_t)b * NOC * KTOT;
    const unsigned short* xbB = xbt + (size_t)b * PPIX * NC;

    // ---- staging source pointers (7 instrs max per thread) ----
    const unsigned short* srcA[4];
    #pragma unroll
    for (int i = 0; i < 4; ++i) {
        int e = i * 4 + w;                 // 0..15
        int s = e * 64 + l;                // A slot 0..1023
        int u = s >> 3, p3 = s & 7;
        int d = p3 ^ (u & 7);
        int kq = d >> 1, sub = d & 1;
        int row = 2 * u + sub;             // 0..255
        srcA[i] = waB + (size_t)row * KTOT + kq * 8;
    }
    const unsigned short* srcB[3];
    int actB[3];
    #pragma unroll
    for (int i = 0; i < 3; ++i) {
        int e = (i + 4) * 4 + w;           // 16..27
        actB[i] = (e < 26);
        int s = (e - 16) * 64 + l;         // B slot 0..767 (only <640 active)
        if (s > 639) s = 639;
        int u = s >> 3, p3 = s & 7;
        int d = p3 ^ (u & 7);
        int kq = d >> 1, sub = d & 1;
        int prow = 2 * u + sub;            // 0..159
        int pg = nt * PXT + prow; if (pg > NPIX - 1) pg = NPIX - 1;
        int py = pg / 56, px = pg - py * 56;
        srcB[i] = xbB + (size_t)((py + 1) * PW + (px + 1)) * NC + kq * 8;
    }
    const int l16 = l * 16;

    auto issue = [&](int tp, int slot) {
        char* sb = lds + slot * SLICE;
        const int s9 = tp >> 3;
        const int dy = (s9 >= 6) ? 2 : ((s9 >= 3) ? 1 : 0);
        const int dx = s9 - dy * 3;
        const int bsh = ((dy - 1) * PW + (dx - 1)) * NC + (tp & 7) * 32;
        #pragma unroll
        for (int i = 0; i < 4; ++i) {
            int e = i * 4 + w;
            __builtin_amdgcn_global_load_lds(
                (const __attribute__((address_space(1))) void*)(srcA[i] + tp * 32),
                (__attribute__((address_space(3))) void*)(sb + e * 1024 + l16), 16, 0, 0);
        }
        #pragma unroll
        for (int i = 0; i < 3; ++i) {
            if (actB[i]) {
                int e = (i + 4) * 4 + w;
                __builtin_amdgcn_global_load_lds(
                    (const __attribute__((address_space(1))) void*)(srcB[i] + bsh),
                    (__attribute__((address_space(3))) void*)(sb + e * 1024 + l16), 16, 0, 0);
            }
        }
    };

    // ---- read-side lane constants ----
    const int subq = ((l >> 4) << 1) | (l & 1);      // (kq<<1)|sub
    const int ulow = (l >> 1) & 7;                   // ((l&15)>>1)&7
    const int aoff0 = (wm * 64 + ((l & 15) >> 1)) * 128 + ((subq ^ ulow) << 4);
    const int boff0 = BOFF + (wn * 40 + ((l & 15) >> 1)) * 128 + ((subq ^ ulow) << 4);

    f32x4 acc[8][5] = {};

    issue(0, 0); issue(1, 1);

    int cs = 0, is2 = 2;
    for (int p = 0; p < 71; ++p) {
        asm volatile("s_waitcnt vmcnt(6)" ::: "memory");
        __builtin_amdgcn_s_barrier();
        __builtin_amdgcn_sched_barrier(0);
        if (p < 70) {
            issue(p + 2, is2);
            ++is2; if (is2 == 3) is2 = 0;
        }
        const char* sb = lds + cs * SLICE;
        ++cs; if (cs == 3) cs = 0;
        bf16x8 af[8];
        #pragma unroll
        for (int m = 0; m < 8; ++m)
            af[m] = *(const bf16x8*)(sb + aoff0 + m * 1024);
        __builtin_amdgcn_s_setprio(1);
        #pragma unroll
        for (int j = 0; j < 5; ++j) {
            bf16x8 bf = *(const bf16x8*)(sb + boff0 + j * 1024);
            #pragma unroll
            for (int m = 0; m < 8; ++m)
                acc[m][j] = __builtin_amdgcn_mfma_f32_16x16x32_bf16(af[m], bf, acc[m][j], 0, 0, 0);
        }
        __builtin_amdgcn_s_setprio(0);
    }
    // final phase 71
    asm volatile("s_waitcnt vmcnt(0)" ::: "memory");
    __builtin_amdgcn_s_barrier();
    __builtin_amdgcn_sched_barrier(0);
    {
        const char* sb = lds + cs * SLICE;
        bf16x8 af[8];
        #pragma unroll
        for (int m = 0; m < 8; ++m)
            af[m] = *(const bf16x8*)(sb + aoff0 + m * 1024);
        #pragma unroll
        for (int j = 0; j < 5; ++j) {
            bf16x8 bf = *(const bf16x8*)(sb + boff0 + j * 1024);
            #pragma unroll
            for (int m = 0; m < 8; ++m)
                acc[m][j] = __builtin_amdgcn_mfma_f32_16x16x32_bf16(af[m], bf, acc[m][j], 0, 0, 0);
        }
    }

    // epilogue: D lane map col = l&15 (pixel), row = (l>>4)*4 + r (oc)
    const int ocb = wm * 128 + ((l >> 4) << 2);
    const int pxb = nt * PXT + wn * 80 + (l & 15);
    #pragma unroll
    for (int i = 0; i < 8; ++i) {
        #pragma unroll
        for (int j = 0; j < 5; ++j) {
            int p = pxb + j * 16;
            if (p < NPIX) {
                float* o = out + ((size_t)(b * NOC + ocb + i * 16)) * NPIX + p;
                o[0]        = acc[i][j][0];
                o[NPIX]     = acc[i][j][1];
                o[2 * NPIX] = acc[i][j][2];
                o[3 * NPIX] = acc[i][j][3];
            }
        }
    }
}

extern "C" void kernel_launch(void* const* d_in, const int* in_sizes, int n_in,
                              void* d_out, int out_size, void* d_ws, size_t ws_size,
                              hipStream_t stream) {
    (void)in_sizes; (void)n_in; (void)out_size; (void)ws_size;
    const float* x   = (const float*)d_in[0];
    const float* rw  = (const float*)d_in[1];
    const float* rb  = (const float*)d_in[2];
    const float* f1w = (const float*)d_in[3];
    const float* f2w = (const float*)d_in[4];
    const float* f2b = (const float*)d_in[5];
    float* out = (float*)d_out;

    char* wsb = (char*)d_ws;
    unsigned short* xbt = (unsigned short*)wsb;
    unsigned short* wa  = (unsigned short*)(wsb + XBT_BYTES);
    float* gap = (float*)(wsb + XBT_BYTES + WA_BYTES);
    float* a2  = (float*)(wsb + XBT_BYTES + WA_BYTES + (size_t)NB * NC * 4);

    hipMemsetAsync(gap, 0, (size_t)NB * NC * 4, stream);
    halo_kernel<<<dim3(32), 256, 0, stream>>>(xbt);
    xpose_kernel<<<dim3(56, 32), 256, 0, stream>>>(x, xbt, gap);
    se_kernel<<<dim3(1), 512, 0, stream>>>(gap, rw, rb, f1w, a2);
    wk_kernel<<<dim3(256), 256, 0, stream>>>(a2, f2w, f2b, wa);
    conv_gemm<<<dim3(640), 256, 0, stream>>>(wa, xbt, out);
}

// Round 6
// 210.140 us; speedup vs baseline: 1.0421x; 1.0421x over previous
//
#include <hip/hip_runtime.h>
#include <hip/hip_bf16.h>
#include <stdint.h>

// ---------------- problem constants ----------------
#define NB   32
#define NC   256
#define NOC  256
#define HWD  56
#define NPIX 3136      // 56*56
#define PW   58        // padded row width
#define PPIX 3364      // 58*58
#define KTOT 2304      // 9 * 256
#define MOD  512       // fc1 out channels
#define GAPD 16

// workspace layout (bytes)
#define XBT_BYTES ((size_t)NB * PPIX * NC * 2)            // 55,115,776
#define WA_BYTES  ((size_t)NB * NOC * KTOT * 2)           // 37,748,736

typedef __bf16 bf16x8 __attribute__((ext_vector_type(8)));
typedef float  f32x4  __attribute__((ext_vector_type(4)));
typedef unsigned short u16x8 __attribute__((ext_vector_type(8)));

__device__ __forceinline__ unsigned short f2bf(float f) {
    union { float f; unsigned int u; } v; v.f = f;
    unsigned int u = v.u;
    return (unsigned short)((u + 0x7FFFu + ((u >> 16) & 1u)) >> 16);
}

// ---------------- P1: SE network (one block, 512 threads) ----------------
__global__ void se_kernel(const float* __restrict__ gap,
                          const float* __restrict__ rw, const float* __restrict__ rb,
                          const float* __restrict__ f1w, float* __restrict__ a2) {
    __shared__ float sgap[NB * NC];
    __shared__ float sg[NB * GAPD];
    int t = threadIdx.x; // 0..511
    #pragma unroll
    for (int i = 0; i < 16; ++i) sgap[i * 512 + t] = gap[i * 512 + t];
    __syncthreads();
    {
        int b = t >> 4, tt = t & 15;
        float s = rb[tt];
        for (int c = 0; c < NC; ++c) s += sgap[b * NC + c] * rw[tt * NC + c];
        sg[b * GAPD + tt] = s;
    }
    __syncthreads();
    for (int i = 0; i < 32; ++i) {
        int o = i * 512 + t;
        int b = o >> 9, m = o & 511;
        float s = 0.f;
        #pragma unroll
        for (int tt = 0; tt < GAPD; ++tt) s += sg[b * GAPD + tt] * f1w[m * GAPD + tt];
        a2[o] = 1.0f / (1.0f + __expf(-s));
    }
}

// ---------------- P2: per-batch conv weights; one block per oc, loop over b ----------------
__global__ void wk_kernel(const float* __restrict__ a2,
                          const float* __restrict__ f2w, const float* __restrict__ f2b,
                          unsigned short* __restrict__ wa) {
    __shared__ float sw[KTOT];
    __shared__ float sbv[KTOT];
    __shared__ float sa[2 * NB];
    int oc = blockIdx.x, c = threadIdx.x;
    const float4* wsrc = (const float4*)(f2w + (size_t)oc * KTOT);
    const float4* bsrc = (const float4*)(f2b + (size_t)oc * KTOT);
    #pragma unroll
    for (int i = 0; i < 3; ++i) {
        int idx = i * 256 + c;
        if (idx < 576) {
            ((float4*)sw)[idx] = wsrc[idx];
            ((float4*)sbv)[idx] = bsrc[idx];
        }
    }
    if (c < 64) sa[c] = a2[(c >> 1) * MOD + 2 * oc + (c & 1)];
    __syncthreads();
    float w9[9], b9[9];
    #pragma unroll
    for (int s = 0; s < 9; ++s) { w9[s] = sw[c * 9 + s]; b9[s] = sbv[c * 9 + s]; }
    for (int b = 0; b < NB; ++b) {
        float a0 = sa[2 * b], a1 = sa[2 * b + 1];
        unsigned short* dst = wa + (size_t)(b * NOC + oc) * KTOT;
        #pragma unroll
        for (int s = 0; s < 9; ++s) {
            float a = ((c * 9 + s) >= 1152) ? a1 : a0;
            dst[s * NC + c] = f2bf(a * w9[s] + b9[s]);
        }
    }
}

// ---------------- P3: zero the halo of xbt ----------------
__global__ void halo_kernel(unsigned short* __restrict__ xbt) {
    int b = blockIdx.x, t = threadIdx.x;
    unsigned short* xb = xbt + (size_t)b * PPIX * NC;
    u16x8 z = {};
    for (int i = t; i < 3712; i += 256) {
        int r = (i >= 1856) ? 1 : 0;
        int c = i - r * 1856;
        int pix = r * (57 * 58) + (c >> 5);
        *(u16x8*)(xb + (size_t)pix * NC + (c & 31) * 8) = z;
    }
    for (int i = t; i < 3584; i += 256) {
        int row = 1 + (i >> 6);
        int side = (i >> 5) & 1;
        int pix = row * PW + side * 57;
        *(u16x8*)(xb + (size_t)pix * NC + (i & 31) * 8) = z;
    }
}

// ---------------- P4: x -> bf16 NHWC with halo, fused GAP partial sums ----------------
#define TSTR 59
__global__ void xpose_kernel(const float* __restrict__ x, unsigned short* __restrict__ xbt,
                             float* __restrict__ gap) {
    __shared__ unsigned short tile[NC * TSTR];
    int py = blockIdx.x, b = blockIdx.y, t = threadIdx.x;
    int wv = t >> 6, l = t & 63;
    const float* xs = x + (size_t)b * NC * NPIX + py * HWD;
    int q = l & 15;
    int rb4 = l >> 4;
    #pragma unroll
    for (int it = 0; it < 16; ++it) {
        int c = wv * 64 + it * 4 + rb4;
        if (q < 14) {
            float4 v = *(const float4*)(xs + (size_t)c * NPIX + q * 4);
            unsigned short* tr = tile + c * TSTR + q * 4;
            tr[0] = f2bf(v.x); tr[1] = f2bf(v.y); tr[2] = f2bf(v.z); tr[3] = f2bf(v.w);
        }
    }
    __syncthreads();
    {
        float s = 0.f;
        #pragma unroll
        for (int px = 0; px < 56; ++px) {
            union { unsigned int u; float f; } cv;
            cv.u = ((unsigned int)tile[t * TSTR + px]) << 16;
            s += cv.f;
        }
        atomicAdd(&gap[b * NC + t], s * (1.0f / NPIX));
    }
    int cch = t & 31, pg = t >> 5;
    for (int i = 0; i < 7; ++i) {
        int px = pg * 7 + i;
        u16x8 v;
        #pragma unroll
        for (int j = 0; j < 8; ++j) v[j] = tile[(cch * 8 + j) * TSTR + px];
        *(u16x8*)(xbt + ((size_t)b * PPIX + (size_t)(1 + py) * PW + 1 + px) * NC + cch * 8) = v;
    }
}

// ---------------- main GEMM: 256oc x 128px tile, 4 waves (128x64 each), ring-3 ----------------
// K = 2304 = 72 phases of BK=32. Slice = A[256][32] (16KB) + B[128][32] (8KB) = 24KB;
// ring-3 = 72KB -> 2 blocks/CU (144KB LDS, 8 waves/CU at <=256 unified regs/wave).
// R2-proven LDS layout (0 conflicts): 1KB unit = 16 rows x 4 chunks of 16B,
// content(row, phys p) = logical chunk p ^ ((row>>1)&3); staged via pre-swizzled
// global source + linear LDS dest. One barrier/phase; counted vmcnt(6), never 0
// until the drain; issue(p+2) after compute(p) (WAR-safe: pre-compute barrier of
// phase p separates it from phase p-1's readers of the same slot).
#define SLICE 24576
#define BOFS  16384

__global__ __launch_bounds__(256, 2) void conv_gemm(
    const unsigned short* __restrict__ wa,   // [32][256][2304] bf16
    const unsigned short* __restrict__ xbt,  // [32][3364][256] bf16 (padded NHWC)
    float* __restrict__ out)                 // [32][256][3136]
{
    __shared__ __attribute__((aligned(16))) char lds[3 * SLICE];  // 73728 B

    // XCD swizzle: 800 blocks = 8 XCD * 100; 4 whole batches per XCD
    const int bid = blockIdx.x;
    const int wg  = (bid & 7) * 100 + (bid >> 3);
    const int b   = wg / 25, nt = wg % 25;

    const int t = threadIdx.x;
    const int w = t >> 6, l = t & 63;            // 4 waves
    const int wm = w >> 1, wn = w & 1;           // 2M x 2N, wave tile 128oc x 64px

    const unsigned short* waB = wa + (size_t)b * NOC * KTOT;
    const unsigned short* xbB = xbt + (size_t)b * PPIX * NC;

    // ---- staging source pointers (R2 mapping; 6 loads/thread/slice) ----
    // within a 1KB unit: lane l -> row l>>2, phys chunk l&3,
    // stored logical chunk sq = (l&3) ^ ((l>>3)&3)
    const int srow = l >> 2;
    const int sq8  = ((l & 3) ^ ((l >> 3) & 3)) * 8;   // element offset of 16B chunk
    const unsigned short* srcA[4];
    #pragma unroll
    for (int i = 0; i < 4; ++i) {
        int row = (i * 4 + w) * 16 + srow;             // A units: 4i + w (0..15)
        srcA[i] = waB + (size_t)row * KTOT + sq8;
    }
    const unsigned short* srcB[2];
    #pragma unroll
    for (int i = 0; i < 2; ++i) {
        int row = (i * 4 + w) * 16 + srow;             // B units: 4i + w (0..7)
        int pg = nt * 128 + row; if (pg > NPIX - 1) pg = NPIX - 1;
        int py = pg / 56, px = pg - py * 56;
        srcB[i] = xbB + (size_t)((py + 1) * PW + (px + 1)) * NC + sq8;
    }
    const int l16 = l * 16;

    auto issue = [&](int tp, int slot) {
        char* sb = lds + slot * SLICE;
        const int koff = tp * 32;
        const int s9 = tp >> 3;
        const int dy = (s9 >= 6) ? 2 : ((s9 >= 3) ? 1 : 0);
        const int dx = s9 - dy * 3;
        const int bsh = ((dy - 1) * PW + (dx - 1)) * NC + (tp & 7) * 32;
        #pragma unroll
        for (int i = 0; i < 4; ++i)
            __builtin_amdgcn_global_load_lds(
                (const __attribute__((address_space(1))) void*)(srcA[i] + koff),
                (__attribute__((address_space(3))) void*)(sb + (i * 4 + w) * 1024 + l16), 16, 0, 0);
        #pragma unroll
        for (int i = 0; i < 2; ++i)
            __builtin_amdgcn_global_load_lds(
                (const __attribute__((address_space(1))) void*)(srcB[i] + bsh),
                (__attribute__((address_space(3))) void*)(sb + BOFS + (i * 4 + w) * 1024 + l16), 16, 0, 0);
    };

    // ---- read-side lane constants (R2-proven, 0 conflicts) ----
    // row within unit = l&15, logical chunk kq = l>>4; phys = kq ^ ((l>>1)&3)
    const int physq16 = (((l >> 4) ^ ((l >> 1) & 3)) << 4);
    const int arow = (l & 15) << 6;

    f32x4 acc[8][4] = {};

    auto compute = [&](int slot) {
        const char* sb = lds + slot * SLICE;
        bf16x8 af[8], bfr[4];
        #pragma unroll
        for (int i = 0; i < 8; ++i)
            af[i] = *(const bf16x8*)(sb + (wm * 8 + i) * 1024 + arow + physq16);
        #pragma unroll
        for (int j = 0; j < 4; ++j)
            bfr[j] = *(const bf16x8*)(sb + BOFS + (wn * 4 + j) * 1024 + arow + physq16);
        __builtin_amdgcn_s_setprio(1);
        #pragma unroll
        for (int i = 0; i < 8; ++i)
            #pragma unroll
            for (int j = 0; j < 4; ++j)
                acc[i][j] = __builtin_amdgcn_mfma_f32_16x16x32_bf16(af[i], bfr[j], acc[i][j], 0, 0, 0);
        __builtin_amdgcn_s_setprio(0);
    };

    issue(0, 0); issue(1, 1);

    int cs = 0;      // slot of phase p
    for (int p = 0; p < 70; ++p) {
        asm volatile("s_waitcnt vmcnt(6)" ::: "memory");   // slice p resident
        __builtin_amdgcn_s_barrier();
        __builtin_amdgcn_sched_barrier(0);
        compute(cs);
        int ns = cs + 2; if (ns >= 3) ns -= 3;
        issue(p + 2, ns);                                  // WAR-safe (see header)
        ++cs; if (cs == 3) cs = 0;
    }
    // p = 70: only slice 71's 6 loads outstanding
    asm volatile("s_waitcnt vmcnt(6)" ::: "memory");
    __builtin_amdgcn_s_barrier();
    __builtin_amdgcn_sched_barrier(0);
    compute(cs);
    ++cs; if (cs == 3) cs = 0;
    // p = 71: drain
    asm volatile("s_waitcnt vmcnt(0)" ::: "memory");
    __builtin_amdgcn_s_barrier();
    __builtin_amdgcn_sched_barrier(0);
    compute(cs);

    // epilogue: D lane map col = l&15 (pixel), row = (l>>4)*4 + r (oc)
    const int ocb = wm * 128 + ((l >> 4) << 2);
    const int pxb = nt * 128 + wn * 64 + (l & 15);
    #pragma unroll
    for (int i = 0; i < 8; ++i) {
        #pragma unroll
        for (int j = 0; j < 4; ++j) {
            int p = pxb + j * 16;
            if (p < NPIX) {
                float* o = out + ((size_t)(b * NOC + ocb + i * 16)) * NPIX + p;
                o[0]        = acc[i][j][0];
                o[NPIX]     = acc[i][j][1];
                o[2 * NPIX] = acc[i][j][2];
                o[3 * NPIX] = acc[i][j][3];
            }
        }
    }
}

extern "C" void kernel_launch(void* const* d_in, const int* in_sizes, int n_in,
                              void* d_out, int out_size, void* d_ws, size_t ws_size,
                              hipStream_t stream) {
    (void)in_sizes; (void)n_in; (void)out_size; (void)ws_size;
    const float* x   = (const float*)d_in[0];
    const float* rw  = (const float*)d_in[1];
    const float* rb  = (const float*)d_in[2];
    const float* f1w = (const float*)d_in[3];
    const float* f2w = (const float*)d_in[4];
    const float* f2b = (const float*)d_in[5];
    float* out = (float*)d_out;

    char* wsb = (char*)d_ws;
    unsigned short* xbt = (unsigned short*)wsb;
    unsigned short* wa  = (unsigned short*)(wsb + XBT_BYTES);
    float* gap = (float*)(wsb + XBT_BYTES + WA_BYTES);
    float* a2  = (float*)(wsb + XBT_BYTES + WA_BYTES + (size_t)NB * NC * 4);

    hipMemsetAsync(gap, 0, (size_t)NB * NC * 4, stream);
    halo_kernel<<<dim3(32), 256, 0, stream>>>(xbt);
    xpose_kernel<<<dim3(56, 32), 256, 0, stream>>>(x, xbt, gap);
    se_kernel<<<dim3(1), 512, 0, stream>>>(gap, rw, rb, f1w, a2);
    wk_kernel<<<dim3(256), 256, 0, stream>>>(a2, f2w, f2b, wa);
    conv_gemm<<<dim3(800), 256, 0, stream>>>(wa, xbt, out);
}